// Round 1
// baseline (280.903 us; speedup 1.0000x reference)
//
#include <hip/hip_runtime.h>

// Xcodec2 ISTFT: B=16, FREQ=513, FRAMES=2048, n_fft=1024, hop=256, win=1024
// out: [16, 1, 524288] fp32

#define B_      16
#define FREQ_   513
#define FRAMES_ 2048
#define NFFT_   1024
#define HOP_    256
#define NH_     512          // half-size complex FFT length
#define PAD_    384          // (1024-256)/2
#define T_OUT_  524288       // (2048-1)*256+1024 - 2*384
#define FPB     16           // frames per workgroup

// LDS layout with XOR swizzle: kills the 16-way bank conflict in the
// bit-reversed read-out phase (varying bits of the bit-reversed index live
// in bits [8:5], which otherwise drop out of bank = addr % 32).
__device__ __forceinline__ int zidx(int i, int f) {
  return i * FPB + (f ^ ((i >> 5) & 15));
}

// ws[0..511]   : float2 twiddles
//   [0..255]   : stage twiddles  e^{+i*pi*j/256}
//   [256..511] : pre-twiddles    e^{+i*pi*k/512} (= e^{+i*2pi*k/1024})
__global__ __launch_bounds__(512) void k_twiddle(float2* __restrict__ tw) {
  const int j = threadIdx.x;
  float s, c;
  if (j < 256) {
    const float ang = 3.14159265358979323846f * (float)j * (1.0f / 256.0f);
    sincosf(ang, &s, &c);
    tw[j] = make_float2(c, s);
  } else {
    const int k = j - 256;
    const float ang = 3.14159265358979323846f * (float)k * (1.0f / 512.0f);
    sincosf(ang, &s, &c);
    tw[256 + k] = make_float2(c, s);
  }
}

// One WG = 16 consecutive frames of one batch.
// irfft(1024) via: Z[k] = E[k] + i O[k] built from X[k], conj(X[512-k]);
// then unnormalized 512-pt inverse DIF FFT (output bit-reversed in place);
// x[2m] = Re z[m] / 512, x[2m+1] = Im z[m] / 512; multiply by window; store.
__global__ __launch_bounds__(256) void k_frames(
    const float* __restrict__ sre, const float* __restrict__ sim,
    const float* __restrict__ win, const float2* __restrict__ tw,
    float* __restrict__ frames) {
  __shared__ float Zre[NH_ * FPB];   // 32 KB
  __shared__ float Zim[NH_ * FPB];   // 32 KB
  const int t  = threadIdx.x;
  const int wg = blockIdx.x;
  const int b  = wg >> 7;            // 128 WGs per batch (2048/16)
  const int f0 = (wg & 127) << 4;
  const size_t base = (size_t)b * FREQ_ * FRAMES_ + f0;
  const float* __restrict__ srb = sre + base;
  const float* __restrict__ sib = sim + base;

  // ---- build Z in LDS (coalesced 64B-row loads along frames axis) ----
  {
    const int f  = t & 15;
    const int kk = t >> 4;           // 0..15
    for (int iter = 0; iter < 16; ++iter) {
      const int k  = (iter << 4) + kk;   // 0..255
      const int k2 = 512 - k;            // 257..512
      float xr1 = srb[(size_t)k  * FRAMES_ + f];
      float xi1 = sib[(size_t)k  * FRAMES_ + f];
      float xr2 = srb[(size_t)k2 * FRAMES_ + f];
      float xi2 = sib[(size_t)k2 * FRAMES_ + f];
      if (k == 0) { xi1 = 0.0f; xi2 = 0.0f; }  // irfft ignores Im of bins 0,512
      const float Er = 0.5f * (xr1 + xr2);
      const float Ei = 0.5f * (xi1 - xi2);
      const float Dr = 0.5f * (xr1 - xr2);     // 0.5 folded into D
      const float Di = 0.5f * (xi1 + xi2);
      const float2 w = tw[256 + k];            // e^{+i*2pi*k/1024}
      const float Or = w.x * Dr - w.y * Di;
      const float Oi = w.x * Di + w.y * Dr;
      // Z[k] = E + iO ; Z[512-k] = conj(E) + i conj(O)
      Zre[zidx(k, f)] = Er - Oi;
      Zim[zidx(k, f)] = Ei + Or;
      if (k != 0) {
        Zre[zidx(k2, f)] = Er + Oi;
        Zim[zidx(k2, f)] = Or - Ei;
      }
    }
    if (t < 16) {                    // k = 256 (self-paired): Z = conj(X[256])
      const int f2 = t;
      Zre[zidx(256, f2)] =  srb[(size_t)256 * FRAMES_ + f2];
      Zim[zidx(256, f2)] = -sib[(size_t)256 * FRAMES_ + f2];
    }
  }
  __syncthreads();

  // ---- 9-stage radix-2 inverse DIF FFT, in place, bit-reversed output ----
  {
    const int f  = t & 15;
    const int j0 = t >> 4;
    int step = 1;
    for (int h = 256; h >= 1; h >>= 1, step <<= 1) {
      for (int r = 0; r < 16; ++r) {
        const int j   = j0 + (r << 4);           // 0..255
        const int pos = j & (h - 1);
        const int i1  = ((j & ~(h - 1)) << 1) | pos;
        const int i2  = i1 + h;
        const int a1 = zidx(i1, f), a2 = zidx(i2, f);
        const float ar = Zre[a1], ai = Zim[a1];
        const float br = Zre[a2], bi = Zim[a2];
        const float sr = ar - br, si = ai - bi;
        const float2 w = tw[pos * step];         // e^{+i*pi*pos/h}
        Zre[a1] = ar + br;
        Zim[a1] = ai + bi;
        Zre[a2] = w.x * sr - w.y * si;
        Zim[a2] = w.x * si + w.y * sr;
      }
      __syncthreads();
    }
  }

  // ---- windowed write-out: z[m] = Z[bitrev9(m)]; coalesced float2 stores ----
  {
    const int fw = t >> 4;          // 16 consecutive threads = one frame
    const int mg = t & 15;
    const float2* __restrict__ win2 = (const float2*)win;
    float2* __restrict__ dst =
        (float2*)(frames + ((size_t)(b * FRAMES_ + f0 + fw)) * NFFT_);
    const float inv = 1.0f / 512.0f;
    for (int r = 0; r < 32; ++r) {
      const int m  = mg + (r << 4);                     // 0..511
      const int mb = (int)(__brev((unsigned)m) >> 23);  // bitrev9
      const int a  = zidx(mb, fw);
      const float zr = Zre[a] * inv;
      const float zi = Zim[a] * inv;
      const float2 wv = win2[m];
      dst[m] = make_float2(zr * wv.x, zi * wv.y);
    }
  }
}

// Gather overlap-add + envelope divide + crop. One float4 of output/thread.
// Any 4-aligned sample group has a uniform contributing-frame range.
__global__ __launch_bounds__(256) void k_ola(
    const float* __restrict__ frames, const float* __restrict__ win,
    float* __restrict__ out) {
  const int gid = blockIdx.x * 256 + threadIdx.x;
  const int b = gid >> 17;              // T_OUT_/4 = 131072 = 2^17
  const int q = gid & 131071;
  const int u = (q << 2) + PAD_;        // uncropped audio index
  const int f_hi = min(FRAMES_ - 1, u >> 8);
  const int f_lo = (u >= 1024) ? (((u - 1024) >> 8) + 1) : 0;
  float ax = 0.f, ay = 0.f, az = 0.f, aw = 0.f;
  float ex = 0.f, ey = 0.f, ez = 0.f, ew = 0.f;
  const float* __restrict__ fb = frames + (size_t)b * FRAMES_ * NFFT_;
  for (int f = f_lo; f <= f_hi; ++f) {
    const int off = u - (f << 8);       // 0..1023, 4-aligned
    const float4 fr = *(const float4*)(fb + (size_t)f * NFFT_ + off);
    const float4 w  = *(const float4*)(win + off);
    ax += fr.x; ay += fr.y; az += fr.z; aw += fr.w;
    ex += w.x * w.x; ey += w.y * w.y; ez += w.z * w.z; ew += w.w * w.w;
  }
  const float4 res = make_float4(ax / ex, ay / ey, az / ez, aw / ew);
  *(float4*)(out + (size_t)b * T_OUT_ + (q << 2)) = res;
}

extern "C" void kernel_launch(void* const* d_in, const int* in_sizes, int n_in,
                              void* d_out, int out_size, void* d_ws, size_t ws_size,
                              hipStream_t stream) {
  const float* sre = (const float*)d_in[0];
  const float* sim = (const float*)d_in[1];
  const float* win = (const float*)d_in[2];
  float2* tw    = (float2*)d_ws;
  float* frames = (float*)((char*)d_ws + 4096);   // 16*2048*1024 floats = 128 MiB
  float* out    = (float*)d_out;

  k_twiddle<<<1, 512, 0, stream>>>(tw);
  k_frames<<<(B_ * FRAMES_) / FPB, 256, 0, stream>>>(sre, sim, win, tw, frames);
  k_ola<<<(B_ * (T_OUT_ / 4)) / 256, 256, 0, stream>>>(frames, win, out);
}

// Round 2
// 225.064 us; speedup vs baseline: 1.2481x; 1.2481x over previous
//
#include <hip/hip_runtime.h>

// Fused Xcodec2 ISTFT: B=16, FREQ=513, FRAMES=2048, n_fft=1024, hop=256, win=1024
// out: [16, 1, 524288] fp32
//
// One WG = 12 hops (3072 output samples) of one batch; computes the 16 frames
// covering them (frames 12*wgq-2 .. 12*wgq+13), irfft via half-size complex
// FFT (4 radix-4 LDS sweeps + 1 radix-2), windows into LDS, overlap-adds from
// LDS, divides by precomputed 1/envelope, writes float2 coalesced.

#define B_      16
#define FREQ_   513
#define FRAMES_ 2048
#define NFFT_   1024
#define HOP_    256
#define NH_     512          // half-size complex FFT length
#define PAD_    384          // (1024-256)/2
#define T_OUT_  524288
#define FPW     16           // frames resident in LDS per WG
#define HPW     12           // useful hops per WG
#define SPW     3072         // output samples per WG
#define NCHUNK  171          // ceil(T_OUT/SPW)

// XOR-swizzled LDS index for the Z arrays (frames fastest, 16 frames).
__device__ __forceinline__ int zidx(int i, int f) {
  return (i << 4) + (f ^ ((i >> 5) & 15));
}

// ws[0..511] float2 twiddles:
//   [0..255]   stage twiddles  e^{+i*pi*j/256}
//   [256..511] pre-twiddles    e^{+i*pi*k/512}
__global__ __launch_bounds__(512) void k_twiddle(float2* __restrict__ tw) {
  const int j = threadIdx.x;
  float s, c;
  if (j < 256) {
    sincosf(3.14159265358979323846f * (float)j * (1.0f / 256.0f), &s, &c);
    tw[j] = make_float2(c, s);
  } else {
    const int k = j - 256;
    sincosf(3.14159265358979323846f * (float)k * (1.0f / 512.0f), &s, &c);
    tw[256 + k] = make_float2(c, s);
  }
}

// invenv[s] = 1 / sum_f win^2(u - 256 f),  u = s + PAD_, valid f only.
__global__ __launch_bounds__(256) void k_env(const float* __restrict__ win,
                                             float* __restrict__ invenv) {
  const int s = blockIdx.x * 256 + threadIdx.x;
  const int u = s + PAD_;
  const int fh = min(FRAMES_ - 1, u >> 8);
  const int fl = (u >= NFFT_) ? (((u - NFFT_) >> 8) + 1) : 0;
  float e = 0.f;
  for (int f = fl; f <= fh; ++f) {
    const float w = win[u - (f << 8)];
    e += w * w;
  }
  invenv[s] = 1.0f / e;
}

__global__ __launch_bounds__(512, 4) void k_fused(
    const float* __restrict__ sre, const float* __restrict__ sim,
    const float* __restrict__ win, const float2* __restrict__ twg,
    const float* __restrict__ invenv, float* __restrict__ out) {
  __shared__ __align__(16) float lds[16384];   // Zre[0..8191], Zim[8192..], later xw
  __shared__ __align__(16) float2 twl[256];    // stage twiddles
  float* __restrict__ Zre = lds;
  float* __restrict__ Zim = lds + 8192;

  const int t   = threadIdx.x;
  const int b   = blockIdx.x & 15;
  const int wgq = blockIdx.x >> 4;
  const int f_base = HPW * wgq - 2;
  const int s0     = SPW * wgq;

  if (t < 256) twl[t] = twg[t];   // synced by the post-build barrier

  // ---- build Z for 16 frames (zero-fill out-of-range frames) ----
  const int f  = t & 15;
  const int kk = t >> 4;               // 0..31
  const int fg = f_base + f;
  const bool fv = (fg >= 0) && (fg < FRAMES_);
  const size_t bbase = (size_t)b * (FREQ_ * FRAMES_);
  const float* __restrict__ srb = sre + bbase;
  const float* __restrict__ sib = sim + bbase;
#pragma unroll
  for (int r = 0; r < 8; ++r) {
    const int k  = (r << 5) + kk;      // 0..255
    const int k2 = NH_ - k;            // 257..512
    float xr1 = fv ? srb[(size_t)k  * FRAMES_ + fg] : 0.f;
    float xi1 = fv ? sib[(size_t)k  * FRAMES_ + fg] : 0.f;
    float xr2 = fv ? srb[(size_t)k2 * FRAMES_ + fg] : 0.f;
    float xi2 = fv ? sib[(size_t)k2 * FRAMES_ + fg] : 0.f;
    if (k == 0) { xi1 = 0.f; xi2 = 0.f; }      // irfft ignores Im of bins 0,512
    const float Er = 0.5f * (xr1 + xr2);
    const float Ei = 0.5f * (xi1 - xi2);
    const float Dr = 0.5f * (xr1 - xr2);
    const float Di = 0.5f * (xi1 + xi2);
    const float2 w = twg[256 + k];             // e^{+i*2pi*k/1024}
    const float Or = w.x * Dr - w.y * Di;
    const float Oi = w.x * Di + w.y * Dr;
    Zre[zidx(k, f)] = Er - Oi;
    Zim[zidx(k, f)] = Ei + Or;
    if (k != 0) {
      Zre[zidx(k2, f)] = Er + Oi;
      Zim[zidx(k2, f)] = Or - Ei;
    }
  }
  if (t < 16) {                        // k = 256: Z = conj(X[256])
    const int fg2 = f_base + t;
    const bool v2 = (fg2 >= 0) && (fg2 < FRAMES_);
    Zre[zidx(256, t)] = v2 ?  srb[(size_t)256 * FRAMES_ + fg2] : 0.f;
    Zim[zidx(256, t)] = v2 ? -sib[(size_t)256 * FRAMES_ + fg2] : 0.f;
  }
  __syncthreads();

  // ---- 4 radix-4 sweeps (combines radix-2 stage pairs h=2q,q) ----
  const int j0 = t >> 4;               // 0..31
#pragma unroll
  for (int sw = 0; sw < 4; ++sw) {
    const int lq = 7 - 2 * sw;         // log2 q: 7,5,3,1
    const int q  = 1 << lq;
#pragma unroll
    for (int r = 0; r < 4; ++r) {
      const int j   = j0 + (r << 5);   // 0..127
      const int pos = j & (q - 1);
      const int blk = j >> lq;
      const int i0  = (blk << (lq + 2)) + pos;
      const int a0 = zidx(i0, f),         a1 = zidx(i0 + q, f);
      const int a2 = zidx(i0 + 2 * q, f), a3 = zidx(i0 + 3 * q, f);
      const float x0r = Zre[a0], x0i = Zim[a0];
      const float x1r = Zre[a1], x1i = Zim[a1];
      const float x2r = Zre[a2], x2i = Zim[a2];
      const float x3r = Zre[a3], x3i = Zim[a3];
      const float2 w1 = twl[pos << (7 - lq)];    // e^{+i pi pos/(2q)}
      const float2 w2 = twl[pos << (8 - lq)];    // e^{+i pi pos/q}
      const float w3r = w1.x * w2.x - w1.y * w2.y;   // w1*w2
      const float w3i = w1.x * w2.y + w1.y * w2.x;
      const float t0r = x0r + x2r, t0i = x0i + x2i;
      const float t1r = x0r - x2r, t1i = x0i - x2i;
      const float t2r = x1r + x3r, t2i = x1i + x3i;
      const float t3r = x1r - x3r, t3i = x1i - x3i;
      const float u2r = t1r - t3i, u2i = t1i + t3r;  // t1 + i*t3
      const float u3r = t1r + t3i, u3i = t1i - t3r;  // t1 - i*t3
      const float s1r = t0r - t2r, s1i = t0i - t2i;
      Zre[a0] = t0r + t2r;
      Zim[a0] = t0i + t2i;
      Zre[a1] = w2.x * s1r - w2.y * s1i;
      Zim[a1] = w2.x * s1i + w2.y * s1r;
      Zre[a2] = w1.x * u2r - w1.y * u2i;
      Zim[a2] = w1.x * u2i + w1.y * u2r;
      Zre[a3] = w3r * u3r - w3i * u3i;
      Zim[a3] = w3r * u3i + w3i * u3r;
    }
    __syncthreads();
  }

  // ---- final radix-2 stage (h=1, twiddle = 1) ----
#pragma unroll
  for (int r = 0; r < 8; ++r) {
    const int j = j0 + (r << 5);       // 0..255
    const int a = zidx(2 * j, f), c = zidx(2 * j + 1, f);
    const float ar = Zre[a], ai = Zim[a];
    const float br = Zre[c], bi = Zim[c];
    Zre[a] = ar + br; Zim[a] = ai + bi;
    Zre[c] = ar - br; Zim[c] = ai - bi;
  }
  __syncthreads();

  // ---- readout: stage windowed time samples through registers into xw ----
  // z[m] = Z[bitrev9(m)]; x[2m]=Re, x[2m+1]=Im; scale 1/512; window.
  {
    const int fw = t >> 5;             // 0..15
    const int mg = t & 31;
    const float2* __restrict__ win2 = (const float2*)win;
    const float inv = 1.0f / 512.0f;
    float sr[16], si[16];
#pragma unroll
    for (int r = 0; r < 16; ++r) {
      const int m = mg + (r << 5);                      // 0..511
      const int p = (int)(__brev((unsigned)m) >> 23);   // bitrev9
      const int a = zidx(p, fw);
      const float2 wv = win2[m];
      sr[r] = Zre[a] * inv * wv.x;
      si[r] = Zim[a] * inv * wv.y;
    }
    __syncthreads();
    float2* __restrict__ xw2 = (float2*)lds;            // [fl][512] float2 pairs
#pragma unroll
    for (int r = 0; r < 16; ++r) {
      const int m = mg + (r << 5);
      xw2[(fw << 9) + m] = make_float2(sr[r], si[r]);
    }
  }
  __syncthreads();

  // ---- overlap-add from LDS, envelope divide, store float2 ----
  {
    const float2* __restrict__ xw2 = (const float2*)lds;
    float* __restrict__ outb = out + (size_t)b * T_OUT_;
#pragma unroll
    for (int r = 0; r < 3; ++r) {
      const int sl = (t + (r << 9)) << 1;   // 0..3070, even
      const int s  = s0 + sl;
      if (s < T_OUT_) {
        const int u  = s + PAD_;
        const int fh = u >> 8;
        const int ob = u & 255;
        float vr = 0.f, vi = 0.f;
#pragma unroll
        for (int jj = 0; jj < 4; ++jj) {
          const int fl  = fh - jj - f_base;          // 0..15 by construction
          const int off = ob + (jj << 8);            // 0..1023, even
          const float2 v = xw2[(fl << 9) + (off >> 1)];
          vr += v.x; vi += v.y;
        }
        const float2 ie = *(const float2*)(invenv + s);
        *(float2*)(outb + s) = make_float2(vr * ie.x, vi * ie.y);
      }
    }
  }
}

extern "C" void kernel_launch(void* const* d_in, const int* in_sizes, int n_in,
                              void* d_out, int out_size, void* d_ws, size_t ws_size,
                              hipStream_t stream) {
  const float* sre = (const float*)d_in[0];
  const float* sim = (const float*)d_in[1];
  const float* win = (const float*)d_in[2];
  float2* tw     = (float2*)d_ws;                       // 4 KB
  float*  invenv = (float*)((char*)d_ws + 4096);        // 2 MB
  float*  out    = (float*)d_out;

  k_twiddle<<<1, 512, 0, stream>>>(tw);
  k_env<<<T_OUT_ / 256, 256, 0, stream>>>(win, invenv);
  k_fused<<<B_ * NCHUNK, 512, 0, stream>>>(sre, sim, win, tw, invenv, out);
}

// Round 3
// 222.428 us; speedup vs baseline: 1.2629x; 1.0119x over previous
//
#include <hip/hip_runtime.h>

// Fused Xcodec2 ISTFT: B=16, FREQ=513, FRAMES=2048, n_fft=1024, hop=256, win=1024
// out: [16, 1, 524288] fp32
//
// irfft(1024) via half-size complex inverse FFT (N=512) done as radix-8
// Stockham: 3 register butterflies, only 2 LDS exchange passes. Window +
// overlap-add + envelope divide fused in the same kernel.

#define B_      16
#define FREQ_   513
#define FRAMES_ 2048
#define NFFT_   1024
#define HOP_    256
#define NH_     512
#define PAD_    384
#define T_OUT_  524288
#define FPW     16           // frames resident per WG
#define HPW     12           // useful hops per WG
#define SPW     3072         // output samples per WG
#define NCHUNK  171          // ceil(T_OUT/SPW)

#define ZSTR    521          // [f][i] float row stride (odd -> 2-way banks max)
#define XWSTR   1041         // [f][s] float row stride (odd)
#define LDSF    16672        // max(2*16*521, 16*1041)

// 8-point inverse DFT (sign +i), DIF, in-place; output slot r = y[brev3(r)].
__device__ __forceinline__ void idft8(float* zr, float* zi) {
  const float C = 0.70710678118654752f;
  float tr, ti;
  // span 4, twiddle W8^p = e^{+2pi i p/8}
  tr = zr[0]-zr[4]; ti = zi[0]-zi[4]; zr[0]+=zr[4]; zi[0]+=zi[4]; zr[4]=tr;        zi[4]=ti;
  tr = zr[1]-zr[5]; ti = zi[1]-zi[5]; zr[1]+=zr[5]; zi[1]+=zi[5]; zr[5]=C*(tr-ti); zi[5]=C*(tr+ti);
  tr = zr[2]-zr[6]; ti = zi[2]-zi[6]; zr[2]+=zr[6]; zi[2]+=zi[6]; zr[6]=-ti;       zi[6]=tr;
  tr = zr[3]-zr[7]; ti = zi[3]-zi[7]; zr[3]+=zr[7]; zi[3]+=zi[7]; zr[7]=-C*(tr+ti); zi[7]=C*(tr-ti);
  // span 2, twiddle W4^p = {1, +i}
  tr = zr[0]-zr[2]; ti = zi[0]-zi[2]; zr[0]+=zr[2]; zi[0]+=zi[2]; zr[2]=tr;  zi[2]=ti;
  tr = zr[1]-zr[3]; ti = zi[1]-zi[3]; zr[1]+=zr[3]; zi[1]+=zi[3]; zr[3]=-ti; zi[3]=tr;
  tr = zr[4]-zr[6]; ti = zi[4]-zi[6]; zr[4]+=zr[6]; zi[4]+=zi[6]; zr[6]=tr;  zi[6]=ti;
  tr = zr[5]-zr[7]; ti = zi[5]-zi[7]; zr[5]+=zr[7]; zi[5]+=zi[7]; zr[7]=-ti; zi[7]=tr;
  // span 1
  tr = zr[0]-zr[1]; ti = zi[0]-zi[1]; zr[0]+=zr[1]; zi[0]+=zi[1]; zr[1]=tr; zi[1]=ti;
  tr = zr[2]-zr[3]; ti = zi[2]-zi[3]; zr[2]+=zr[3]; zi[2]+=zi[3]; zr[3]=tr; zi[3]=ti;
  tr = zr[4]-zr[5]; ti = zi[4]-zi[5]; zr[4]+=zr[5]; zi[4]+=zi[5]; zr[5]=tr; zi[5]=ti;
  tr = zr[6]-zr[7]; ti = zi[6]-zi[7]; zr[6]+=zr[7]; zi[6]+=zi[7]; zr[7]=tr; zi[7]=ti;
}

// prep: block 0 -> tw512[i]=e^{+2pi i/512}; block 1 -> pre[k]=e^{+i pi k/512};
// blocks 2.. -> invenv (1 / squared-window OLA envelope).
__global__ __launch_bounds__(256) void k_prep(const float* __restrict__ win,
                                              float2* __restrict__ tw512,
                                              float2* __restrict__ pre,
                                              float* __restrict__ invenv) {
  const int blk = blockIdx.x, t = threadIdx.x;
  if (blk == 0) {
    float s, c;
    sincosf((float)t * (6.2831853071795864769f / 512.f), &s, &c);
    tw512[t] = make_float2(c, s);
    sincosf((float)(t + 256) * (6.2831853071795864769f / 512.f), &s, &c);
    tw512[t + 256] = make_float2(c, s);
  } else if (blk == 1) {
    float s, c;
    sincosf((float)t * (3.1415926535897932385f / 512.f), &s, &c);
    pre[t] = make_float2(c, s);
    sincosf((float)(t + 256) * (3.1415926535897932385f / 512.f), &s, &c);
    pre[t + 256] = make_float2(c, s);
    if (t == 0) pre[512] = make_float2(-1.f, 0.f);
  } else {
    const int s_ = (blk - 2) * 256 + t;
    if (s_ < T_OUT_) {
      const int u  = s_ + PAD_;
      const int fh = min(FRAMES_ - 1, u >> 8);
      const int fl = (u >= NFFT_) ? (((u - NFFT_) >> 8) + 1) : 0;
      float e = 0.f;
      for (int f = fl; f <= fh; ++f) { const float w = win[u - (f << 8)]; e += w * w; }
      invenv[s_] = 1.0f / e;
    }
  }
}

__global__ __launch_bounds__(512, 4) void k_fused(
    const float* __restrict__ sre, const float* __restrict__ sim,
    const float* __restrict__ win, const float2* __restrict__ tw512,
    const float2* __restrict__ pre, const float* __restrict__ invenv,
    float* __restrict__ out) {
  __shared__ float lds[LDSF];
  float* __restrict__ ZR = lds;
  float* __restrict__ ZI = lds + 16 * ZSTR;

  const int t  = threadIdx.x;
  const int f  = t & 15;               // frame slot (coalescing: frames fastest)
  const int j0 = t >> 4;               // 0..31 butterfly lane
  const int b   = blockIdx.x & 15;
  const int wgq = blockIdx.x >> 4;
  const int f_base = HPW * wgq - 2;
  const int s0     = SPW * wgq;
  const int fg = f_base + f;
  const bool fv = (fg >= 0) && (fg < FRAMES_);
  const int fgc = fv ? fg : 0;
  const float scale = fv ? (0.5f / 512.0f) : 0.0f;   // 0.5 (E/O) * 1/512 (ifft norm)
  const size_t bbase = (size_t)b * (FREQ_ * FRAMES_);
  const float* __restrict__ srb = sre + bbase + fgc;
  const float* __restrict__ sib = sim + bbase + fgc;
  const int brev3[8] = {0, 4, 2, 6, 1, 5, 3, 7};

  // ---- pass 1: build Z from global (registers) + radix-8 + twiddle + LDS write
#pragma unroll
  for (int half = 0; half < 2; ++half) {
    const int j = j0 + 32 * half;
    float zr[8], zi[8];
#pragma unroll
    for (int m = 0; m < 8; ++m) {
      const int i  = j + (m << 6);
      const int k2 = NH_ - i;
      float xr1 = srb[(size_t)i  * FRAMES_];
      float xi1 = sib[(size_t)i  * FRAMES_];
      float xr2 = srb[(size_t)k2 * FRAMES_];
      float xi2 = sib[(size_t)k2 * FRAMES_];
      if (i == 0) { xi1 = 0.f; xi2 = 0.f; }   // irfft ignores Im of bins 0,512
      const float Er = xr1 + xr2, Ei = xi1 - xi2;
      const float Dr = xr1 - xr2, Di = xi1 + xi2;
      const float2 w = pre[i];                // e^{+2pi i * i /1024}
      const float Or = w.x * Dr - w.y * Di;
      const float Oi = w.x * Di + w.y * Dr;
      zr[m] = (Er - Oi) * scale;
      zi[m] = (Ei + Or) * scale;
    }
    idft8(zr, zi);
#pragma unroll
    for (int r = 0; r < 8; ++r) {
      const int mp = brev3[r];
      const int a  = f * ZSTR + j + (mp << 6);
      if (mp == 0) { ZR[a] = zr[r]; ZI[a] = zi[r]; }
      else {
        const float2 w = tw512[j * mp];       // W_512^{j*mp}
        ZR[a] = zr[r] * w.x - zi[r] * w.y;
        ZI[a] = zr[r] * w.y + zi[r] * w.x;
      }
    }
  }
  __syncthreads();

  // ---- pass 2: LDS exchange + radix-8 + twiddle (in-place per butterfly) ----
#pragma unroll
  for (int half = 0; half < 2; ++half) {
    const int j   = j0 + 32 * half;
    const int pos = j & 7, blk = j >> 3;
    const int i0  = (blk << 6) + pos;
    float zr[8], zi[8];
#pragma unroll
    for (int m = 0; m < 8; ++m) {
      const int a = f * ZSTR + i0 + (m << 3);
      zr[m] = ZR[a]; zi[m] = ZI[a];
    }
    idft8(zr, zi);
#pragma unroll
    for (int r = 0; r < 8; ++r) {
      const int mp = brev3[r];
      const int a  = f * ZSTR + i0 + (mp << 3);
      if (mp == 0) { ZR[a] = zr[r]; ZI[a] = zi[r]; }
      else {
        const float2 w = tw512[(pos * mp) << 3];   // W_64^{pos*mp}
        ZR[a] = zr[r] * w.x - zi[r] * w.y;
        ZI[a] = zr[r] * w.y + zi[r] * w.x;
      }
    }
  }
  __syncthreads();

  // ---- pass 3: read into regs, radix-8, then overlay LDS with windowed xw ----
  float yr[16], yi[16];
#pragma unroll
  for (int half = 0; half < 2; ++half) {
    const int j = j0 + 32 * half;
#pragma unroll
    for (int m = 0; m < 8; ++m) {
      const int a = f * ZSTR + (j << 3) + m;
      yr[half * 8 + m] = ZR[a];
      yi[half * 8 + m] = ZI[a];
    }
    idft8(yr + half * 8, yi + half * 8);
  }
  __syncthreads();                       // all Z reads done before overlay

  // output position: sample m = 64*brev3(r) + c; x[2m]=Re*win, x[2m+1]=Im*win
  float* __restrict__ XW = lds;          // [f][s], stride XWSTR
  const int c0 = ((j0 & 7) << 3) + (j0 >> 3);
  const float2* __restrict__ win2 = (const float2*)win;
#pragma unroll
  for (int half = 0; half < 2; ++half) {
    const int c = c0 + 4 * half;
#pragma unroll
    for (int r = 0; r < 8; ++r) {
      const int mp = brev3[r];
      const int m  = (mp << 6) + c;
      const float2 wv = win2[m];
      const int a = f * XWSTR + (m << 1);
      XW[a]     = yr[half * 8 + r] * wv.x;
      XW[a + 1] = yi[half * 8 + r] * wv.y;
    }
  }
  __syncthreads();

  // ---- overlap-add from LDS + envelope divide + coalesced float2 store ----
  float* __restrict__ outb = out + (size_t)b * T_OUT_;
#pragma unroll
  for (int r = 0; r < 3; ++r) {
    const int sl = (t + (r << 9)) << 1;
    const int s  = s0 + sl;
    if (s < T_OUT_) {
      const int u  = s + PAD_;
      const int fh = u >> 8, ob = u & 255;
      float vr = 0.f, vi = 0.f;
#pragma unroll
      for (int jj = 0; jj < 4; ++jj) {
        const int fl = fh - jj - f_base;          // 0..15 by construction
        const int a  = fl * XWSTR + ob + (jj << 8);
        vr += XW[a]; vi += XW[a + 1];
      }
      const float2 ie = *(const float2*)(invenv + s);
      *(float2*)(outb + s) = make_float2(vr * ie.x, vi * ie.y);
    }
  }
}

extern "C" void kernel_launch(void* const* d_in, const int* in_sizes, int n_in,
                              void* d_out, int out_size, void* d_ws, size_t ws_size,
                              hipStream_t stream) {
  const float* sre = (const float*)d_in[0];
  const float* sim = (const float*)d_in[1];
  const float* win = (const float*)d_in[2];
  float2* tw512  = (float2*)d_ws;                        // 512 entries
  float2* pre    = tw512 + 512;                          // 513 entries
  float*  invenv = (float*)((char*)d_ws + 16384);        // 2 MB
  float*  out    = (float*)d_out;

  k_prep<<<2 + (T_OUT_ + 255) / 256, 256, 0, stream>>>(win, tw512, pre, invenv);
  k_fused<<<B_ * NCHUNK, 512, 0, stream>>>(sre, sim, win, tw512, pre, invenv, out);
}

// Round 4
// 221.853 us; speedup vs baseline: 1.2662x; 1.0026x over previous
//
#include <hip/hip_runtime.h>

// Fused Xcodec2 ISTFT: B=16, FREQ=513, FRAMES=2048, n_fft=1024, hop=256, win=1024
// out: [16, 1, 524288] fp32
//
// irfft(1024) via half-size complex inverse FFT (N=512) as radix-8 Stockham:
// 3 register butterflies, 2 LDS exchanges (float2/b64, conflict-free layout).
// Window + overlap-add + envelope divide fused. 1024 threads/WG, 2 WG/CU
// (32 waves = 100% occupancy), each thread owns one radix-8 group per pass.

#define B_      16
#define FREQ_   513
#define FRAMES_ 2048
#define NFFT_   1024
#define HOP_    256
#define NH_     512
#define PAD_    384
#define T_OUT_  524288
#define HPW     12           // useful hops per WG
#define SPW     3072         // output samples per WG
#define NCHUNK  171          // ceil(T_OUT/SPW)

#define ZSTR2   513          // float2 row stride for Z   (odd -> uniform bank pairs)
#define XWSTR   513          // float row stride for XWe/XWo planes (odd)
#define LDSF    16416        // floats: 16*513*2 (Z overlaid later by XWe+XWo)

// 8-point inverse DFT (sign +i), DIF, in-place; output slot r holds y[brev3(r)].
__device__ __forceinline__ void idft8(float* zr, float* zi) {
  const float C = 0.70710678118654752f;
  float tr, ti;
  tr = zr[0]-zr[4]; ti = zi[0]-zi[4]; zr[0]+=zr[4]; zi[0]+=zi[4]; zr[4]=tr;         zi[4]=ti;
  tr = zr[1]-zr[5]; ti = zi[1]-zi[5]; zr[1]+=zr[5]; zi[1]+=zi[5]; zr[5]=C*(tr-ti);  zi[5]=C*(tr+ti);
  tr = zr[2]-zr[6]; ti = zi[2]-zi[6]; zr[2]+=zr[6]; zi[2]+=zi[6]; zr[6]=-ti;        zi[6]=tr;
  tr = zr[3]-zr[7]; ti = zi[3]-zi[7]; zr[3]+=zr[7]; zi[3]+=zi[7]; zr[7]=-C*(tr+ti); zi[7]=C*(tr-ti);
  tr = zr[0]-zr[2]; ti = zi[0]-zi[2]; zr[0]+=zr[2]; zi[0]+=zi[2]; zr[2]=tr;  zi[2]=ti;
  tr = zr[1]-zr[3]; ti = zi[1]-zi[3]; zr[1]+=zr[3]; zi[1]+=zi[3]; zr[3]=-ti; zi[3]=tr;
  tr = zr[4]-zr[6]; ti = zi[4]-zi[6]; zr[4]+=zr[6]; zi[4]+=zi[6]; zr[6]=tr;  zi[6]=ti;
  tr = zr[5]-zr[7]; ti = zi[5]-zi[7]; zr[5]+=zr[7]; zi[5]+=zi[7]; zr[7]=-ti; zi[7]=tr;
  tr = zr[0]-zr[1]; ti = zi[0]-zi[1]; zr[0]+=zr[1]; zi[0]+=zi[1]; zr[1]=tr; zi[1]=ti;
  tr = zr[2]-zr[3]; ti = zi[2]-zi[3]; zr[2]+=zr[3]; zi[2]+=zi[3]; zr[3]=tr; zi[3]=ti;
  tr = zr[4]-zr[5]; ti = zi[4]-zi[5]; zr[4]+=zr[5]; zi[4]+=zi[5]; zr[5]=tr; zi[5]=ti;
  tr = zr[6]-zr[7]; ti = zi[6]-zi[7]; zr[6]+=zr[7]; zi[6]+=zi[7]; zr[7]=tr; zi[7]=ti;
}

// prep: block 0 -> tw512[i]=e^{+2pi i/512}; block 1 -> pre[k]=e^{+i pi k/512};
// blocks 2.. -> invenv (1 / squared-window OLA envelope).
__global__ __launch_bounds__(256) void k_prep(const float* __restrict__ win,
                                              float2* __restrict__ tw512,
                                              float2* __restrict__ pre,
                                              float* __restrict__ invenv) {
  const int blk = blockIdx.x, t = threadIdx.x;
  if (blk == 0) {
    float s, c;
    sincosf((float)t * (6.2831853071795864769f / 512.f), &s, &c);
    tw512[t] = make_float2(c, s);
    sincosf((float)(t + 256) * (6.2831853071795864769f / 512.f), &s, &c);
    tw512[t + 256] = make_float2(c, s);
  } else if (blk == 1) {
    float s, c;
    sincosf((float)t * (3.1415926535897932385f / 512.f), &s, &c);
    pre[t] = make_float2(c, s);
    sincosf((float)(t + 256) * (3.1415926535897932385f / 512.f), &s, &c);
    pre[t + 256] = make_float2(c, s);
    if (t == 0) pre[512] = make_float2(-1.f, 0.f);
  } else {
    const int s_ = (blk - 2) * 256 + t;
    if (s_ < T_OUT_) {
      const int u  = s_ + PAD_;
      const int fh = min(FRAMES_ - 1, u >> 8);
      const int fl = (u >= NFFT_) ? (((u - NFFT_) >> 8) + 1) : 0;
      float e = 0.f;
      for (int f = fl; f <= fh; ++f) { const float w = win[u - (f << 8)]; e += w * w; }
      invenv[s_] = 1.0f / e;
    }
  }
}

__global__ __launch_bounds__(1024, 8) void k_fused(
    const float* __restrict__ sre, const float* __restrict__ sim,
    const float* __restrict__ win, const float2* __restrict__ tw512,
    const float2* __restrict__ pre, const float* __restrict__ invenv,
    float* __restrict__ out) {
  __shared__ __align__(16) float lds[LDSF];
  float2* __restrict__ Z2 = (float2*)lds;      // [f][i], stride ZSTR2

  const int t = threadIdx.x;
  const int f = t & 15;                // frame slot (16 consecutive frames/load)
  const int j = t >> 4;                // 0..63 butterfly lane
  const int b   = blockIdx.x & 15;
  const int wgq = blockIdx.x >> 4;
  const int f_base = HPW * wgq - 2;
  const int s0     = SPW * wgq;
  const int fg = f_base + f;
  const bool fv = (fg >= 0) && (fg < FRAMES_);
  const int fgc = fv ? fg : 0;
  const float scale = fv ? (0.5f / 512.0f) : 0.0f;  // 0.5 (E/O) * 1/512 (ifft norm)
  const size_t bbase = (size_t)b * (FREQ_ * FRAMES_);
  const float* __restrict__ srb = sre + bbase + fgc;
  const float* __restrict__ sib = sim + bbase + fgc;
  const int brev3[8] = {0, 4, 2, 6, 1, 5, 3, 7};

  // ---- pass 1: build Z from global + radix-8 + twiddle + b64 LDS write ----
  {
    float zr[8], zi[8];
#pragma unroll
    for (int m = 0; m < 8; ++m) {
      const int i  = j + (m << 6);     // 0..511
      const int k2 = NH_ - i;
      float xr1 = srb[(size_t)i  * FRAMES_];
      float xi1 = sib[(size_t)i  * FRAMES_];
      float xr2 = srb[(size_t)k2 * FRAMES_];
      float xi2 = sib[(size_t)k2 * FRAMES_];
      if (i == 0) { xi1 = 0.f; xi2 = 0.f; }  // irfft ignores Im of bins 0,512
      const float Er = xr1 + xr2, Ei = xi1 - xi2;
      const float Dr = xr1 - xr2, Di = xi1 + xi2;
      const float2 w = pre[i];               // e^{+2pi i * i /1024}
      const float Or = w.x * Dr - w.y * Di;
      const float Oi = w.x * Di + w.y * Dr;
      zr[m] = (Er - Oi) * scale;
      zi[m] = (Ei + Or) * scale;
    }
    idft8(zr, zi);
    float2* __restrict__ zrow = Z2 + f * ZSTR2 + j;
#pragma unroll
    for (int r = 0; r < 8; ++r) {
      const int mp = brev3[r];
      if (mp == 0) zrow[0] = make_float2(zr[r], zi[r]);
      else {
        const float2 w = tw512[j * mp];      // W_512^{j*mp}
        zrow[mp << 6] = make_float2(zr[r] * w.x - zi[r] * w.y,
                                    zr[r] * w.y + zi[r] * w.x);
      }
    }
  }
  __syncthreads();

  // ---- pass 2: b64 LDS exchange + radix-8 + twiddle ----
  {
    const int pos = j & 7, blk = j >> 3;
    float2* __restrict__ zrow = Z2 + f * ZSTR2 + (blk << 6) + pos;
    float zr[8], zi[8];
#pragma unroll
    for (int m = 0; m < 8; ++m) {
      const float2 v = zrow[m << 3];
      zr[m] = v.x; zi[m] = v.y;
    }
    idft8(zr, zi);
#pragma unroll
    for (int r = 0; r < 8; ++r) {
      const int mp = brev3[r];
      if (mp == 0) zrow[0] = make_float2(zr[r], zi[r]);
      else {
        const float2 w = tw512[(pos * mp) << 3];   // W_64^{pos*mp}
        zrow[mp << 3] = make_float2(zr[r] * w.x - zi[r] * w.y,
                                    zr[r] * w.y + zi[r] * w.x);
      }
    }
  }
  __syncthreads();

  // ---- pass 3: b64 read + radix-8 (final, twiddle-free outputs) ----
  float yr[8], yi[8];
  {
    const float2* __restrict__ zrow = Z2 + f * ZSTR2 + (j << 3);
#pragma unroll
    for (int m = 0; m < 8; ++m) {
      const float2 v = zrow[m];
      yr[m] = v.x; yi[m] = v.y;
    }
  }
  idft8(yr, yi);
  __syncthreads();                     // all Z reads done before XW overlay

  // ---- window + scatter to de-interleaved XW planes ----
  // time sample pair m: x[2m]=Re z[m], x[2m+1]=Im z[m]; m = brev3(r)*64 + c.
  float* __restrict__ XWe = lds;                    // [f][m] even samples (Re)
  float* __restrict__ XWo = lds + 16 * XWSTR;       // [f][m] odd samples  (Im)
  {
    const int c = ((j & 7) << 3) + (j >> 3);        // Stockham output perm
    const float2* __restrict__ win2 = (const float2*)win;
    float* __restrict__ er = XWe + f * XWSTR + c;
    float* __restrict__ od = XWo + f * XWSTR + c;
#pragma unroll
    for (int r = 0; r < 8; ++r) {
      const int mp = brev3[r];
      const float2 wv = win2[(mp << 6) + c];
      er[mp << 6] = yr[r] * wv.x;
      od[mp << 6] = yi[r] * wv.y;
    }
  }
  __syncthreads();

  // ---- overlap-add from LDS + envelope divide + coalesced float2 store ----
  float* __restrict__ outb = out + (size_t)b * T_OUT_;
#pragma unroll
  for (int rr = 0; rr < 2; ++rr) {
    const int idx = t + (rr << 10);    // 0..1535 used
    if (idx < 1536) {
      const int s = s0 + (idx << 1);
      if (s < T_OUT_) {
        const int u   = s + PAD_;
        const int fh  = u >> 8;
        const int me0 = (u & 255) >> 1;     // even-sample index within hop
        float vr = 0.f, vi = 0.f;
#pragma unroll
        for (int jj = 0; jj < 4; ++jj) {
          const int fl = fh - jj - f_base;  // 0..15 by construction
          const int a  = fl * XWSTR + me0 + (jj << 7);
          vr += XWe[a]; vi += XWo[a];
        }
        const float2 ie = *(const float2*)(invenv + s);
        *(float2*)(outb + s) = make_float2(vr * ie.x, vi * ie.y);
      }
    }
  }
}

extern "C" void kernel_launch(void* const* d_in, const int* in_sizes, int n_in,
                              void* d_out, int out_size, void* d_ws, size_t ws_size,
                              hipStream_t stream) {
  const float* sre = (const float*)d_in[0];
  const float* sim = (const float*)d_in[1];
  const float* win = (const float*)d_in[2];
  float2* tw512  = (float2*)d_ws;                        // 512 entries
  float2* pre    = tw512 + 512;                          // 513 entries
  float*  invenv = (float*)((char*)d_ws + 16384);        // 2 MB
  float*  out    = (float*)d_out;

  k_prep<<<2 + (T_OUT_ + 255) / 256, 256, 0, stream>>>(win, tw512, pre, invenv);
  k_fused<<<B_ * NCHUNK, 1024, 0, stream>>>(sre, sim, win, tw512, pre, invenv, out);
}